// Round 6
// baseline (5193.083 us; speedup 1.0000x reference)
//
#include <hip/hip_runtime.h>

#define TT 512
#define NSTEP 511

typedef _Float16 half8v __attribute__((ext_vector_type(8)));
typedef float floatx4 __attribute__((ext_vector_type(4)));

#if __has_builtin(__builtin_amdgcn_exp2f)
#define FAST_EXP2 __builtin_amdgcn_exp2f
#else
#define FAST_EXP2 exp2f
#endif
#if __has_builtin(__builtin_amdgcn_rcpf)
#define FAST_RCP __builtin_amdgcn_rcpf
#else
#define FAST_RCP(x) (1.0f/(x))
#endif

__device__ __forceinline__ float fast_tanh(float x) {
    float e = FAST_EXP2(x * 2.885390081777927f);
    return 1.0f - 2.0f * FAST_RCP(1.0f + e);
}

__device__ __forceinline__ void split_f16(float x, _Float16& hi, _Float16& lo) {
    hi = (_Float16)x;
    lo = (_Float16)(x - (float)hi);   // exact residual, then f16 round
}

// Pack 4 f32 -> hi uint2 (4×f16) + lo uint2 (4×f16 residuals) via
// v_cvt_pkrtz_f16_f32. RTZ on hi is fine: lo absorbs hi's rounding exactly.
__device__ __forceinline__ void split_pack4(const float x0, const float x1,
                                            const float x2, const float x3,
                                            uint2& uH, uint2& uL) {
    auto h01 = __builtin_amdgcn_cvt_pkrtz(x0, x1);   // __fp16 x2
    auto h23 = __builtin_amdgcn_cvt_pkrtz(x2, x3);
    auto l01 = __builtin_amdgcn_cvt_pkrtz(x0 - (float)h01[0], x1 - (float)h01[1]);
    auto l23 = __builtin_amdgcn_cvt_pkrtz(x2 - (float)h23[0], x3 - (float)h23[1]);
    uH.x = __builtin_bit_cast(unsigned int, h01);
    uH.y = __builtin_bit_cast(unsigned int, h23);
    uL.x = __builtin_bit_cast(unsigned int, l01);
    uL.y = __builtin_bit_cast(unsigned int, l23);
}

// Two waves (128 threads) per block; block owns TWO independent 16-batch
// tiles (t=0,1; 32 batches total, grid=B/32=512 -> 2 blocks/CU, 1 wave/SIMD).
// Rationale (r5 counters): MfmaUtil+VALUBusy = 91% -> pipes serialized by the
// single dependency chain. Two chains per wave share the weight registers and
// interleave: chain A's VALU epilogue overlaps chain B's MFMAs.
// Wave w owns M-rows [32w,32w+32) of L1/L2 and rows [16w,16w+16) of L3/state.
// A-frag: A[m=lane&15][k=quad*8+j]; B-frag: B[k=quad*8+j][n=lane&15];
// C: col(N)=lane&15, row(M)=quad*4+reg. 3-way hi/lo f16 split (fp32 acc).
__global__ __launch_bounds__(128, 1)
void cde_fused(const float* __restrict__ times,
               const float* __restrict__ grads,   // (B, T, 3)
               const float* __restrict__ w1, const float* __restrict__ b1,
               const float* __restrict__ w2, const float* __restrict__ b2,
               const float* __restrict__ w3, const float* __restrict__ b3,
               const float* __restrict__ w_enc, const float* __restrict__ b_enc,
               const float* __restrict__ w_ro, const float* __restrict__ b_ro,
               float* __restrict__ out)
{
    const int tid  = threadIdx.x;      // 0..127
    const int wid  = tid >> 6;         // wave id: 0,1
    const int lane = tid & 63;
    const int col  = lane & 15;        // batch-in-tile (N) / weight row (A-m)
    const int quad = lane >> 4;        // 0..3
    const int base = blockIdx.x << 5;  // global batch base (32/block)

    __shared__ __align__(16) _Float16 zbufH[32][40];   // [n][k], pad->40
    __shared__ __align__(16) _Float16 zbufL[32][40];
    __shared__ __align__(16) _Float16 h1bufH[32][72];  // [n][k], pad->72
    __shared__ __align__(16) _Float16 h1bufL[32][72];
    __shared__ __align__(16) _Float16 h2bufH[32][72];
    __shared__ __align__(16) _Float16 h2bufL[32][72];
    __shared__ __align__(16) float    dqbuf[32][4];
    __shared__ float robuf[32];

    // -------- weights -> f16 hi/lo A-fragments (this wave's halves) ---------
    // Shared by both tiles — the big VGPR investment is amortized 2x.
    half8v w1fH[2], w1fL[2], w2fH[2][2], w2fL[2][2], w3fH[3][2], w3fL[3][2];
    #pragma unroll
    for (int tt = 0; tt < 2; ++tt) {
        const int T = 2*wid + tt;
        const float* p = w1 + (16*T + col)*32 + quad*8;
        #pragma unroll
        for (int j = 0; j < 8; ++j) {
            _Float16 hi, lo; split_f16(p[j], hi, lo);
            w1fH[tt][j] = hi; w1fL[tt][j] = lo;
        }
    }
    #pragma unroll
    for (int tt = 0; tt < 2; ++tt) {
        const int T = 2*wid + tt;
        #pragma unroll
        for (int kt = 0; kt < 2; ++kt) {
            const float* p = w2 + (16*T + col)*64 + kt*32 + quad*8;
            #pragma unroll
            for (int j = 0; j < 8; ++j) {
                _Float16 hi, lo; split_f16(p[j], hi, lo);
                w2fH[tt][kt][j] = hi; w2fL[tt][kt][j] = lo;
            }
        }
    }
    #pragma unroll
    for (int c = 0; c < 3; ++c) {
        const int row = (16*wid + col)*3 + c;
        #pragma unroll
        for (int kt = 0; kt < 2; ++kt) {
            const float* p = w3 + row*64 + kt*32 + quad*8;
            #pragma unroll
            for (int j = 0; j < 8; ++j) {
                _Float16 hi, lo; split_f16(p[j], hi, lo);
                w3fH[c][kt][j] = hi; w3fL[c][kt][j] = lo;
            }
        }
    }

    // biases in C-layout
    float b1c[2][4], b2c[2][4], b3c[3][4];
    #pragma unroll
    for (int tt = 0; tt < 2; ++tt) {
        const int T = 2*wid + tt;
        #pragma unroll
        for (int r = 0; r < 4; ++r) {
            b1c[tt][r] = b1[16*T + 4*quad + r];
            b2c[tt][r] = b2[16*T + 4*quad + r];
        }
    }
    #pragma unroll
    for (int c = 0; c < 3; ++c)
        #pragma unroll
        for (int r = 0; r < 4; ++r)
            b3c[c][r] = b3[(16*wid + 4*quad + r)*3 + c];

    // state z rows owned by this wave (both tiles start identical)
    float z[2][4];
    #pragma unroll
    for (int r = 0; r < 4; ++r) {
        const int h = 16*wid + 4*quad + r;
        const float e = w_enc[h] + b_enc[h];   // encoder([1.0])
        z[0][r] = e; z[1][r] = e;
    }
    const float dt = times[1] - times[0];

    // dq staging: threads 0..95 fetch one (b,c) stream (32 batches x 3 ch)
    const int lcl = tid < 96 ? tid : 95;
    const int bl  = lcl / 3;
    const int cc  = lcl - 3*bl;
    const float* gp = grads + (long)(base + bl)*(TT*3) + cc;
    const bool dqact = tid < 96;
    float dqreg = gp[0];

    static constexpr float AT[6][5] = {
        {0.f, 0.f, 0.f, 0.f, 0.f},
        {0.161f, 0.f, 0.f, 0.f, 0.f},
        {-0.008480655492356989f, 0.335480655492357f, 0.f, 0.f, 0.f},
        {2.8971530571054935f, -6.359448489975075f, 4.3622954328695815f, 0.f, 0.f},
        {5.325864828439257f, -11.748883564062828f, 7.4955393428898365f,
         -0.09249506636175525f, 0.f},
        {5.86145544294642f, -12.92096931784711f, 8.159367898576159f,
         -0.071584973281401f, -0.028269050394068383f}};
    static constexpr float BT[6] = {
        0.09646076681806523f, 0.01f, 0.4798896504144996f, 1.379008574103742f,
        -3.290069515436081f, 2.324710524099774f};

    float kk[2][6][4];
    float dqv[2][3] = {{0.f,0.f,0.f},{0.f,0.f,0.f}};

    for (int n = 0; n < NSTEP; ++n) {
        if (dqact) *(&dqbuf[0][0] + (bl*4 + cc)) = dqreg * dt;

        #pragma unroll
        for (int s = 0; s < 6; ++s) {
            // stage argument for both tiles (independent VALU chains)
            #pragma unroll
            for (int t = 0; t < 2; ++t) {
                float za[4];
                #pragma unroll
                for (int r = 0; r < 4; ++r) {
                    float v = z[t][r];
                    #pragma unroll
                    for (int j = 0; j < s; ++j) v += AT[s][j] * kk[t][j][r];
                    za[r] = v;
                }
                uint2 uH, uL;
                split_pack4(za[0], za[1], za[2], za[3], uH, uL);
                *(uint2*)&zbufH[16*t + col][16*wid + 4*quad] = uH;
                *(uint2*)&zbufL[16*t + col][16*wid + 4*quad] = uL;
            }
            __syncthreads();
            if (s == 0) {
                #pragma unroll
                for (int t = 0; t < 2; ++t) {
                    const float4 dv = *(const float4*)&dqbuf[16*t + col][0];
                    dqv[t][0] = dv.x; dqv[t][1] = dv.y; dqv[t][2] = dv.z;
                }
                const int nn = (n + 1 < NSTEP) ? (n + 1) : (NSTEP - 1);
                dqreg = gp[nn * 3];          // prefetch next step's gradient
            }
            half8v zfH[2], zfL[2];
            #pragma unroll
            for (int t = 0; t < 2; ++t) {
                zfH[t] = *(const half8v*)&zbufH[16*t + col][quad*8];
                zfL[t] = *(const half8v*)&zbufL[16*t + col][quad*8];
            }

            // ---- layer 1: this wave's 32 rows, both tiles ----
            #pragma unroll
            for (int t = 0; t < 2; ++t) {
                #pragma unroll
                for (int tt = 0; tt < 2; ++tt) {
                    floatx4 acc = {b1c[tt][0], b1c[tt][1], b1c[tt][2], b1c[tt][3]};
                    acc = __builtin_amdgcn_mfma_f32_16x16x32_f16(w1fH[tt], zfH[t], acc, 0, 0, 0);
                    acc = __builtin_amdgcn_mfma_f32_16x16x32_f16(w1fL[tt], zfH[t], acc, 0, 0, 0);
                    acc = __builtin_amdgcn_mfma_f32_16x16x32_f16(w1fH[tt], zfL[t], acc, 0, 0, 0);
                    uint2 uH, uL;
                    split_pack4(fast_tanh(acc[0]), fast_tanh(acc[1]),
                                fast_tanh(acc[2]), fast_tanh(acc[3]), uH, uL);
                    *(uint2*)&h1bufH[16*t + col][32*wid + 16*tt + 4*quad] = uH;
                    *(uint2*)&h1bufL[16*t + col][32*wid + 16*tt + 4*quad] = uL;
                }
            }
            __syncthreads();
            half8v h1f0H[2], h1f1H[2], h1f0L[2], h1f1L[2];
            #pragma unroll
            for (int t = 0; t < 2; ++t) {
                h1f0H[t] = *(const half8v*)&h1bufH[16*t + col][quad*8];
                h1f1H[t] = *(const half8v*)&h1bufH[16*t + col][32 + quad*8];
                h1f0L[t] = *(const half8v*)&h1bufL[16*t + col][quad*8];
                h1f1L[t] = *(const half8v*)&h1bufL[16*t + col][32 + quad*8];
            }

            // ---- layer 2: this wave's 32 rows, both tiles ----
            #pragma unroll
            for (int t = 0; t < 2; ++t) {
                #pragma unroll
                for (int tt = 0; tt < 2; ++tt) {
                    floatx4 acc = {b2c[tt][0], b2c[tt][1], b2c[tt][2], b2c[tt][3]};
                    acc = __builtin_amdgcn_mfma_f32_16x16x32_f16(w2fH[tt][0], h1f0H[t], acc, 0, 0, 0);
                    acc = __builtin_amdgcn_mfma_f32_16x16x32_f16(w2fL[tt][0], h1f0H[t], acc, 0, 0, 0);
                    acc = __builtin_amdgcn_mfma_f32_16x16x32_f16(w2fH[tt][0], h1f0L[t], acc, 0, 0, 0);
                    acc = __builtin_amdgcn_mfma_f32_16x16x32_f16(w2fH[tt][1], h1f1H[t], acc, 0, 0, 0);
                    acc = __builtin_amdgcn_mfma_f32_16x16x32_f16(w2fL[tt][1], h1f1H[t], acc, 0, 0, 0);
                    acc = __builtin_amdgcn_mfma_f32_16x16x32_f16(w2fH[tt][1], h1f1L[t], acc, 0, 0, 0);
                    uint2 uH, uL;
                    split_pack4(fast_tanh(acc[0]), fast_tanh(acc[1]),
                                fast_tanh(acc[2]), fast_tanh(acc[3]), uH, uL);
                    *(uint2*)&h2bufH[16*t + col][32*wid + 16*tt + 4*quad] = uH;
                    *(uint2*)&h2bufL[16*t + col][32*wid + 16*tt + 4*quad] = uL;
                }
            }
            __syncthreads();
            half8v h2f0H[2], h2f1H[2], h2f0L[2], h2f1L[2];
            #pragma unroll
            for (int t = 0; t < 2; ++t) {
                h2f0H[t] = *(const half8v*)&h2bufH[16*t + col][quad*8];
                h2f1H[t] = *(const half8v*)&h2bufH[16*t + col][32 + quad*8];
                h2f0L[t] = *(const half8v*)&h2bufL[16*t + col][quad*8];
                h2f1L[t] = *(const half8v*)&h2bufL[16*t + col][32 + quad*8];
            }

            // ---- layer 3: c = 0..2 of this wave's half, both tiles ----
            #pragma unroll
            for (int t = 0; t < 2; ++t) {
                floatx4 a3[3];
                #pragma unroll
                for (int c = 0; c < 3; ++c) {
                    floatx4 acc = {b3c[c][0], b3c[c][1], b3c[c][2], b3c[c][3]};
                    acc = __builtin_amdgcn_mfma_f32_16x16x32_f16(w3fH[c][0], h2f0H[t], acc, 0, 0, 0);
                    acc = __builtin_amdgcn_mfma_f32_16x16x32_f16(w3fL[c][0], h2f0H[t], acc, 0, 0, 0);
                    acc = __builtin_amdgcn_mfma_f32_16x16x32_f16(w3fH[c][0], h2f0L[t], acc, 0, 0, 0);
                    acc = __builtin_amdgcn_mfma_f32_16x16x32_f16(w3fH[c][1], h2f1H[t], acc, 0, 0, 0);
                    acc = __builtin_amdgcn_mfma_f32_16x16x32_f16(w3fL[c][1], h2f1H[t], acc, 0, 0, 0);
                    acc = __builtin_amdgcn_mfma_f32_16x16x32_f16(w3fH[c][1], h2f1L[t], acc, 0, 0, 0);
                    a3[c] = acc;
                }
                #pragma unroll
                for (int r = 0; r < 4; ++r)
                    kk[t][s][r] = a3[0][r]*dqv[t][0] + a3[1][r]*dqv[t][1]
                                + a3[2][r]*dqv[t][2];
            }
        }

        // z += sum_i B_i * k_i (both tiles)
        #pragma unroll
        for (int t = 0; t < 2; ++t)
            #pragma unroll
            for (int r = 0; r < 4; ++r) {
                float v = z[t][r];
                #pragma unroll
                for (int j = 0; j < 6; ++j) v += BT[j] * kk[t][j][r];
                z[t][r] = v;
            }
    }

    // ---- readout: logit[b] = sum_h z[h][b]*w_ro[h] + b_ro; out = sigmoid ----
    float part[2];
    #pragma unroll
    for (int t = 0; t < 2; ++t) {
        float p = 0.f;
        #pragma unroll
        for (int r = 0; r < 4; ++r)
            p += z[t][r] * w_ro[16*wid + 4*quad + r];
        p += __shfl_xor(p, 16, 64);
        p += __shfl_xor(p, 32, 64);
        part[t] = p;
        if (wid == 1 && lane < 16) robuf[16*t + col] = p;
    }
    __syncthreads();
    if (wid == 0 && lane < 16) {
        #pragma unroll
        for (int t = 0; t < 2; ++t) {
            const float x = part[t] + robuf[16*t + col] + b_ro[0];
            out[base + 16*t + col] =
                FAST_RCP(1.0f + FAST_EXP2(-1.4426950408889634f * x));
        }
    }
}

extern "C" void kernel_launch(void* const* d_in, const int* in_sizes, int n_in,
                              void* d_out, int out_size, void* d_ws, size_t ws_size,
                              hipStream_t stream) {
    const float* times = (const float*)d_in[0];
    const float* grads = (const float*)d_in[1];
    const float* w1    = (const float*)d_in[2];
    const float* b1    = (const float*)d_in[3];
    const float* w2    = (const float*)d_in[4];
    const float* b2    = (const float*)d_in[5];
    const float* w3    = (const float*)d_in[6];
    const float* b3    = (const float*)d_in[7];
    const float* w_enc = (const float*)d_in[8];
    const float* b_enc = (const float*)d_in[9];
    const float* w_ro  = (const float*)d_in[10];
    const float* b_ro  = (const float*)d_in[11];

    const int B = in_sizes[1] / (TT * 3);   // 16384
    dim3 grid(B / 32), block(128);
    hipLaunchKernelGGL(cde_fused, grid, block, 0, stream,
                       times, grads, w1, b1, w2, b2, w3, b3,
                       w_enc, b_enc, w_ro, b_ro, (float*)d_out);
}

// Round 8
// 4420.526 us; speedup vs baseline: 1.1748x; 1.1748x over previous
//
#include <hip/hip_runtime.h>

#define TT 512
#define NSTEP 511

typedef _Float16 half8v __attribute__((ext_vector_type(8)));
typedef float floatx4 __attribute__((ext_vector_type(4)));

#if __has_builtin(__builtin_amdgcn_exp2f)
#define FAST_EXP2 __builtin_amdgcn_exp2f
#else
#define FAST_EXP2 exp2f
#endif
#if __has_builtin(__builtin_amdgcn_rcpf)
#define FAST_RCP __builtin_amdgcn_rcpf
#else
#define FAST_RCP(x) (1.0f/(x))
#endif

__device__ __forceinline__ float fast_tanh(float x) {
    float e = FAST_EXP2(x * 2.885390081777927f);
    return 1.0f - 2.0f * FAST_RCP(1.0f + e);
}

__device__ __forceinline__ void split_f16(float x, _Float16& hi, _Float16& lo) {
    hi = (_Float16)x;
    lo = (_Float16)(x - (float)hi);   // exact residual, then f16 round
}

// Pack 4 f32 -> hi uint2 (4×f16) + lo uint2 (4×f16 residuals) via
// v_cvt_pkrtz_f16_f32. RTZ on hi is fine: lo absorbs hi's rounding exactly.
__device__ __forceinline__ void split_pack4(const float x0, const float x1,
                                            const float x2, const float x3,
                                            uint2& uH, uint2& uL) {
    auto h01 = __builtin_amdgcn_cvt_pkrtz(x0, x1);   // __fp16 x2
    auto h23 = __builtin_amdgcn_cvt_pkrtz(x2, x3);
    auto l01 = __builtin_amdgcn_cvt_pkrtz(x0 - (float)h01[0], x1 - (float)h01[1]);
    auto l23 = __builtin_amdgcn_cvt_pkrtz(x2 - (float)h23[0], x3 - (float)h23[1]);
    uH.x = __builtin_bit_cast(unsigned int, h01);
    uH.y = __builtin_bit_cast(unsigned int, h23);
    uL.x = __builtin_bit_cast(unsigned int, l01);
    uL.y = __builtin_bit_cast(unsigned int, l23);
}

// Two waves (128 threads) per 16-batch tile (r5 structure, best: 4420 µs).
// NEW (r7): de-phase co-resident blocks. r5/r6 counters show
// MfmaUtil+VALUBusy ~ 91%/82% with ~zero pipe overlap: identical
// per-block instruction streams phase-lock the 4 blocks/CU, so all waves
// hit MFMA bursts together (contend) then VALU bursts together. A one-time
// s_sleep stagger at entry persists for the whole 511-step integration
// (blocks never re-sync) and lets one block's MFMA burst overlap another's
// VALU burst on the shared SIMDs. Key (blockIdx>>8)^blockIdx covers both
// plausible co-residency patterns (stride-256 XCD round-robin / chunked).
// Wave w owns M-rows [32w,32w+32) of L1/L2 and rows [16w,16w+16) of L3/z.
// A-frag: A[m=lane&15][k=quad*8+j]; B-frag: B[k=quad*8+j][n=lane&15];
// C: col(N)=lane&15, row(M)=quad*4+reg. 3-way hi/lo f16 split (fp32 acc).
__global__ __launch_bounds__(128, 2)
void cde_fused(const float* __restrict__ times,
               const float* __restrict__ grads,   // (B, T, 3)
               const float* __restrict__ w1, const float* __restrict__ b1,
               const float* __restrict__ w2, const float* __restrict__ b2,
               const float* __restrict__ w3, const float* __restrict__ b3,
               const float* __restrict__ w_enc, const float* __restrict__ b_enc,
               const float* __restrict__ w_ro, const float* __restrict__ b_ro,
               float* __restrict__ out)
{
    // ---- anti-phase stagger (see header comment) ----
    {
        const int key = ((blockIdx.x >> 8) ^ blockIdx.x) & 3;
        switch (key) {
            case 1: __builtin_amdgcn_s_sleep(9);  break;   // ~576 cy
            case 2: __builtin_amdgcn_s_sleep(18); break;   // ~1152 cy
            case 3: __builtin_amdgcn_s_sleep(27); break;   // ~1728 cy
            default: break;
        }
    }

    const int tid  = threadIdx.x;      // 0..127
    const int wid  = tid >> 6;         // wave id: 0,1
    const int lane = tid & 63;
    const int col  = lane & 15;        // batch-in-tile (N) / weight row (A-m)
    const int quad = lane >> 4;        // 0..3
    const int base = blockIdx.x << 4;  // global batch base

    __shared__ __align__(16) _Float16 zbufH[16][40];   // [n][k], pad->40
    __shared__ __align__(16) _Float16 zbufL[16][40];
    __shared__ __align__(16) _Float16 h1bufH[16][72];  // [n][k], pad->72
    __shared__ __align__(16) _Float16 h1bufL[16][72];
    __shared__ __align__(16) _Float16 h2bufH[16][72];
    __shared__ __align__(16) _Float16 h2bufL[16][72];
    __shared__ __align__(16) float    dqbuf[16][4];
    __shared__ float robuf[16];

    // -------- weights -> f16 hi/lo A-fragments (this wave's halves) ---------
    half8v w1fH[2], w1fL[2], w2fH[2][2], w2fL[2][2], w3fH[3][2], w3fL[3][2];
    #pragma unroll
    for (int tt = 0; tt < 2; ++tt) {
        const int T = 2*wid + tt;
        const float* p = w1 + (16*T + col)*32 + quad*8;
        #pragma unroll
        for (int j = 0; j < 8; ++j) {
            _Float16 hi, lo; split_f16(p[j], hi, lo);
            w1fH[tt][j] = hi; w1fL[tt][j] = lo;
        }
    }
    #pragma unroll
    for (int tt = 0; tt < 2; ++tt) {
        const int T = 2*wid + tt;
        #pragma unroll
        for (int kt = 0; kt < 2; ++kt) {
            const float* p = w2 + (16*T + col)*64 + kt*32 + quad*8;
            #pragma unroll
            for (int j = 0; j < 8; ++j) {
                _Float16 hi, lo; split_f16(p[j], hi, lo);
                w2fH[tt][kt][j] = hi; w2fL[tt][kt][j] = lo;
            }
        }
    }
    // L3: wave w takes c=0..2 of rows h = 16*wid + m (orig row = h*3+c).
    #pragma unroll
    for (int c = 0; c < 3; ++c) {
        const int row = (16*wid + col)*3 + c;
        #pragma unroll
        for (int kt = 0; kt < 2; ++kt) {
            const float* p = w3 + row*64 + kt*32 + quad*8;
            #pragma unroll
            for (int j = 0; j < 8; ++j) {
                _Float16 hi, lo; split_f16(p[j], hi, lo);
                w3fH[c][kt][j] = hi; w3fL[c][kt][j] = lo;
            }
        }
    }

    // biases in C-layout
    float b1c[2][4], b2c[2][4], b3c[3][4];
    #pragma unroll
    for (int tt = 0; tt < 2; ++tt) {
        const int T = 2*wid + tt;
        #pragma unroll
        for (int r = 0; r < 4; ++r) {
            b1c[tt][r] = b1[16*T + 4*quad + r];
            b2c[tt][r] = b2[16*T + 4*quad + r];
        }
    }
    #pragma unroll
    for (int c = 0; c < 3; ++c)
        #pragma unroll
        for (int r = 0; r < 4; ++r)
            b3c[c][r] = b3[(16*wid + 4*quad + r)*3 + c];

    // state z rows owned by this wave: h = 16*wid + 4*quad + r
    float z[4];
    #pragma unroll
    for (int r = 0; r < 4; ++r) {
        const int h = 16*wid + 4*quad + r;
        z[r] = w_enc[h] + b_enc[h];   // encoder([1.0])
    }
    const float dt = times[1] - times[0];

    // dq staging: threads 0..47 (wave 0) fetch one (b,c) stream
    const int lcl = tid < 48 ? tid : 47;
    const int bl  = lcl / 3;
    const int cc  = lcl - 3*bl;
    const float* gp = grads + (long)(base + bl)*(TT*3) + cc;
    const bool dqact = tid < 48;
    float dqreg = gp[0];

    static constexpr float AT[6][5] = {
        {0.f, 0.f, 0.f, 0.f, 0.f},
        {0.161f, 0.f, 0.f, 0.f, 0.f},
        {-0.008480655492356989f, 0.335480655492357f, 0.f, 0.f, 0.f},
        {2.8971530571054935f, -6.359448489975075f, 4.3622954328695815f, 0.f, 0.f},
        {5.325864828439257f, -11.748883564062828f, 7.4955393428898365f,
         -0.09249506636175525f, 0.f},
        {5.86145544294642f, -12.92096931784711f, 8.159367898576159f,
         -0.071584973281401f, -0.028269050394068383f}};
    static constexpr float BT[6] = {
        0.09646076681806523f, 0.01f, 0.4798896504144996f, 1.379008574103742f,
        -3.290069515436081f, 2.324710524099774f};

    float kk[6][4];
    float dq0 = 0.f, dq1 = 0.f, dq2 = 0.f;

    for (int n = 0; n < NSTEP; ++n) {
        if (dqact) *(&dqbuf[0][0] + (bl*4 + cc)) = dqreg * dt;

        #pragma unroll
        for (int s = 0; s < 6; ++s) {
            // stage argument (this wave's 16 rows), C-layout
            float za[4];
            #pragma unroll
            for (int r = 0; r < 4; ++r) {
                float v = z[r];
                #pragma unroll
                for (int j = 0; j < s; ++j) v += AT[s][j] * kk[j][r];
                za[r] = v;
            }
            {
                uint2 uH, uL;
                split_pack4(za[0], za[1], za[2], za[3], uH, uL);
                *(uint2*)&zbufH[col][16*wid + 4*quad] = uH;
                *(uint2*)&zbufL[col][16*wid + 4*quad] = uL;
            }
            __syncthreads();
            if (s == 0) {
                const float4 dv = *(const float4*)&dqbuf[col][0];
                dq0 = dv.x; dq1 = dv.y; dq2 = dv.z;
                const int nn = (n + 1 < NSTEP) ? (n + 1) : (NSTEP - 1);
                dqreg = gp[nn * 3];          // prefetch next step's gradient
            }
            const half8v zfH = *(const half8v*)&zbufH[col][quad*8];
            const half8v zfL = *(const half8v*)&zbufL[col][quad*8];

            // ---- layer 1: this wave's 32 rows ----
            #pragma unroll
            for (int tt = 0; tt < 2; ++tt) {
                floatx4 acc = {b1c[tt][0], b1c[tt][1], b1c[tt][2], b1c[tt][3]};
                acc = __builtin_amdgcn_mfma_f32_16x16x32_f16(w1fH[tt], zfH, acc, 0, 0, 0);
                acc = __builtin_amdgcn_mfma_f32_16x16x32_f16(w1fL[tt], zfH, acc, 0, 0, 0);
                acc = __builtin_amdgcn_mfma_f32_16x16x32_f16(w1fH[tt], zfL, acc, 0, 0, 0);
                uint2 uH, uL;
                split_pack4(fast_tanh(acc[0]), fast_tanh(acc[1]),
                            fast_tanh(acc[2]), fast_tanh(acc[3]), uH, uL);
                *(uint2*)&h1bufH[col][32*wid + 16*tt + 4*quad] = uH;
                *(uint2*)&h1bufL[col][32*wid + 16*tt + 4*quad] = uL;
            }
            __syncthreads();
            const half8v h1f0H = *(const half8v*)&h1bufH[col][quad*8];
            const half8v h1f1H = *(const half8v*)&h1bufH[col][32 + quad*8];
            const half8v h1f0L = *(const half8v*)&h1bufL[col][quad*8];
            const half8v h1f1L = *(const half8v*)&h1bufL[col][32 + quad*8];

            // ---- layer 2: this wave's 32 rows ----
            #pragma unroll
            for (int tt = 0; tt < 2; ++tt) {
                floatx4 acc = {b2c[tt][0], b2c[tt][1], b2c[tt][2], b2c[tt][3]};
                acc = __builtin_amdgcn_mfma_f32_16x16x32_f16(w2fH[tt][0], h1f0H, acc, 0, 0, 0);
                acc = __builtin_amdgcn_mfma_f32_16x16x32_f16(w2fL[tt][0], h1f0H, acc, 0, 0, 0);
                acc = __builtin_amdgcn_mfma_f32_16x16x32_f16(w2fH[tt][0], h1f0L, acc, 0, 0, 0);
                acc = __builtin_amdgcn_mfma_f32_16x16x32_f16(w2fH[tt][1], h1f1H, acc, 0, 0, 0);
                acc = __builtin_amdgcn_mfma_f32_16x16x32_f16(w2fL[tt][1], h1f1H, acc, 0, 0, 0);
                acc = __builtin_amdgcn_mfma_f32_16x16x32_f16(w2fH[tt][1], h1f1L, acc, 0, 0, 0);
                uint2 uH, uL;
                split_pack4(fast_tanh(acc[0]), fast_tanh(acc[1]),
                            fast_tanh(acc[2]), fast_tanh(acc[3]), uH, uL);
                *(uint2*)&h2bufH[col][32*wid + 16*tt + 4*quad] = uH;
                *(uint2*)&h2bufL[col][32*wid + 16*tt + 4*quad] = uL;
            }
            __syncthreads();
            const half8v h2f0H = *(const half8v*)&h2bufH[col][quad*8];
            const half8v h2f1H = *(const half8v*)&h2bufH[col][32 + quad*8];
            const half8v h2f0L = *(const half8v*)&h2bufL[col][quad*8];
            const half8v h2f1L = *(const half8v*)&h2bufL[col][32 + quad*8];

            // ---- layer 3: c = 0..2 of this wave's hh half ----
            floatx4 a3[3];
            #pragma unroll
            for (int c = 0; c < 3; ++c) {
                floatx4 acc = {b3c[c][0], b3c[c][1], b3c[c][2], b3c[c][3]};
                acc = __builtin_amdgcn_mfma_f32_16x16x32_f16(w3fH[c][0], h2f0H, acc, 0, 0, 0);
                acc = __builtin_amdgcn_mfma_f32_16x16x32_f16(w3fL[c][0], h2f0H, acc, 0, 0, 0);
                acc = __builtin_amdgcn_mfma_f32_16x16x32_f16(w3fH[c][0], h2f0L, acc, 0, 0, 0);
                acc = __builtin_amdgcn_mfma_f32_16x16x32_f16(w3fH[c][1], h2f1H, acc, 0, 0, 0);
                acc = __builtin_amdgcn_mfma_f32_16x16x32_f16(w3fL[c][1], h2f1H, acc, 0, 0, 0);
                acc = __builtin_amdgcn_mfma_f32_16x16x32_f16(w3fH[c][1], h2f1L, acc, 0, 0, 0);
                a3[c] = acc;
            }
            #pragma unroll
            for (int r = 0; r < 4; ++r)
                kk[s][r] = a3[0][r]*dq0 + a3[1][r]*dq1 + a3[2][r]*dq2;
        }

        // z += sum_i B_i * k_i
        #pragma unroll
        for (int r = 0; r < 4; ++r) {
            float v = z[r];
            #pragma unroll
            for (int j = 0; j < 6; ++j) v += BT[j] * kk[j][r];
            z[r] = v;
        }
    }

    // ---- readout: logit[b] = sum_h z[h][b]*w_ro[h] + b_ro; out = sigmoid ----
    float part = 0.f;
    #pragma unroll
    for (int r = 0; r < 4; ++r)
        part += z[r] * w_ro[16*wid + 4*quad + r];
    part += __shfl_xor(part, 16, 64);
    part += __shfl_xor(part, 32, 64);
    if (wid == 1 && lane < 16) robuf[col] = part;
    __syncthreads();
    if (wid == 0 && lane < 16) {
        const float x = part + robuf[col] + b_ro[0];
        out[base + col] = FAST_RCP(1.0f + FAST_EXP2(-1.4426950408889634f * x));
    }
}

extern "C" void kernel_launch(void* const* d_in, const int* in_sizes, int n_in,
                              void* d_out, int out_size, void* d_ws, size_t ws_size,
                              hipStream_t stream) {
    const float* times = (const float*)d_in[0];
    const float* grads = (const float*)d_in[1];
    const float* w1    = (const float*)d_in[2];
    const float* b1    = (const float*)d_in[3];
    const float* w2    = (const float*)d_in[4];
    const float* b2    = (const float*)d_in[5];
    const float* w3    = (const float*)d_in[6];
    const float* b3    = (const float*)d_in[7];
    const float* w_enc = (const float*)d_in[8];
    const float* b_enc = (const float*)d_in[9];
    const float* w_ro  = (const float*)d_in[10];
    const float* b_ro  = (const float*)d_in[11];

    const int B = in_sizes[1] / (TT * 3);   // 16384
    dim3 grid(B / 16), block(128);
    hipLaunchKernelGGL(cde_fused, grid, block, 0, stream,
                       times, grads, w1, b1, w2, b2, w3, b3,
                       w_enc, b_enc, w_ro, b_ro, (float*)d_out);
}

// Round 9
// 4407.908 us; speedup vs baseline: 1.1781x; 1.0029x over previous
//
#include <hip/hip_runtime.h>

#define TT 512
#define NSTEP 511

typedef _Float16 half8v __attribute__((ext_vector_type(8)));
typedef float floatx4 __attribute__((ext_vector_type(4)));

#if __has_builtin(__builtin_amdgcn_exp2f)
#define FAST_EXP2 __builtin_amdgcn_exp2f
#else
#define FAST_EXP2 exp2f
#endif
#if __has_builtin(__builtin_amdgcn_rcpf)
#define FAST_RCP __builtin_amdgcn_rcpf
#else
#define FAST_RCP(x) (1.0f/(x))
#endif

__device__ __forceinline__ float fast_tanh(float x) {
    float e = FAST_EXP2(x * 2.885390081777927f);
    return 1.0f - 2.0f * FAST_RCP(1.0f + e);
}

__device__ __forceinline__ void split_f16(float x, _Float16& hi, _Float16& lo) {
    hi = (_Float16)x;
    lo = (_Float16)(x - (float)hi);   // exact residual, then f16 round
}

// Pack 4 f32 -> hi uint2 (4×f16) + lo uint2 (4×f16 residuals) via
// v_cvt_pkrtz_f16_f32. RTZ on hi is fine: lo absorbs hi's rounding exactly.
__device__ __forceinline__ void split_pack4(const float x0, const float x1,
                                            const float x2, const float x3,
                                            uint2& uH, uint2& uL) {
    auto h01 = __builtin_amdgcn_cvt_pkrtz(x0, x1);   // __fp16 x2
    auto h23 = __builtin_amdgcn_cvt_pkrtz(x2, x3);
    auto l01 = __builtin_amdgcn_cvt_pkrtz(x0 - (float)h01[0], x1 - (float)h01[1]);
    auto l23 = __builtin_amdgcn_cvt_pkrtz(x2 - (float)h23[0], x3 - (float)h23[1]);
    uH.x = __builtin_bit_cast(unsigned int, h01);
    uH.y = __builtin_bit_cast(unsigned int, h23);
    uL.x = __builtin_bit_cast(unsigned int, l01);
    uL.y = __builtin_bit_cast(unsigned int, l23);
}

// r9: drain-amortization. Corrected counter model (r8): VALUBusy includes
// MFMA issue (v_mfma_* is VALU-class), so true state is MFMA 34% + VALU ~23%
// + ~40% idle, and r3 proved the idle is NOT coverable by TLP (all waves
// lockstep on the same barriers). The idle = 3 barrier-drain windows per
// stage (LDS write -> barrier -> LDS read latency). This version puts TWO
// independent 16-batch tiles in one 256-thread block: waves 2t,2t+1 run the
// unchanged r5 per-wave code on tile t (hw = row-half). Barriers now serve
// 2 tiles of work per drain -> drain cost per unit work halves. Per-wave
// VGPR/work identical to r5 (4420 µs best); grid 512 -> 2 blocks/CU,
// 8 waves/CU (same TLP). Unlike r6, the 2nd tile lives in OTHER waves'
// registers, so the compiler cannot serialize the chains.
// A-frag: A[m=lane&15][k=quad*8+j]; B-frag: B[k=quad*8+j][n=lane&15];
// C: col(N)=lane&15, row(M)=quad*4+reg. 3-way hi/lo f16 split (fp32 acc).
__global__ __launch_bounds__(256, 2)
void cde_fused(const float* __restrict__ times,
               const float* __restrict__ grads,   // (B, T, 3)
               const float* __restrict__ w1, const float* __restrict__ b1,
               const float* __restrict__ w2, const float* __restrict__ b2,
               const float* __restrict__ w3, const float* __restrict__ b3,
               const float* __restrict__ w_enc, const float* __restrict__ b_enc,
               const float* __restrict__ w_ro, const float* __restrict__ b_ro,
               float* __restrict__ out)
{
    const int tid  = threadIdx.x;      // 0..255
    const int wid  = tid >> 6;         // wave id: 0..3
    const int t    = wid >> 1;         // tile within block: 0,1
    const int hw   = wid & 1;          // row-half within tile
    const int lane = tid & 63;
    const int col  = lane & 15;        // batch-in-tile (N) / weight row (A-m)
    const int quad = lane >> 4;        // 0..3
    const int base = blockIdx.x << 5;  // global batch base (32/block)

    __shared__ __align__(16) _Float16 zbufH[2][16][40];   // [t][n][k], pad->40
    __shared__ __align__(16) _Float16 zbufL[2][16][40];
    __shared__ __align__(16) _Float16 h1bufH[2][16][72];  // [t][n][k], pad->72
    __shared__ __align__(16) _Float16 h1bufL[2][16][72];
    __shared__ __align__(16) _Float16 h2bufH[2][16][72];
    __shared__ __align__(16) _Float16 h2bufL[2][16][72];
    __shared__ __align__(16) float    dqbuf[2][16][4];
    __shared__ float robuf[2][16];

    // -------- weights -> f16 hi/lo A-fragments (this wave's halves) ---------
    // Row assignment depends only on hw; both tiles' waves load the same rows.
    half8v w1fH[2], w1fL[2], w2fH[2][2], w2fL[2][2], w3fH[3][2], w3fL[3][2];
    #pragma unroll
    for (int tt = 0; tt < 2; ++tt) {
        const int T = 2*hw + tt;
        const float* p = w1 + (16*T + col)*32 + quad*8;
        #pragma unroll
        for (int j = 0; j < 8; ++j) {
            _Float16 hi, lo; split_f16(p[j], hi, lo);
            w1fH[tt][j] = hi; w1fL[tt][j] = lo;
        }
    }
    #pragma unroll
    for (int tt = 0; tt < 2; ++tt) {
        const int T = 2*hw + tt;
        #pragma unroll
        for (int kt = 0; kt < 2; ++kt) {
            const float* p = w2 + (16*T + col)*64 + kt*32 + quad*8;
            #pragma unroll
            for (int j = 0; j < 8; ++j) {
                _Float16 hi, lo; split_f16(p[j], hi, lo);
                w2fH[tt][kt][j] = hi; w2fL[tt][kt][j] = lo;
            }
        }
    }
    // L3: this wave takes c=0..2 of rows h = 16*hw + m (orig row = h*3+c).
    #pragma unroll
    for (int c = 0; c < 3; ++c) {
        const int row = (16*hw + col)*3 + c;
        #pragma unroll
        for (int kt = 0; kt < 2; ++kt) {
            const float* p = w3 + row*64 + kt*32 + quad*8;
            #pragma unroll
            for (int j = 0; j < 8; ++j) {
                _Float16 hi, lo; split_f16(p[j], hi, lo);
                w3fH[c][kt][j] = hi; w3fL[c][kt][j] = lo;
            }
        }
    }

    // biases in C-layout
    float b1c[2][4], b2c[2][4], b3c[3][4];
    #pragma unroll
    for (int tt = 0; tt < 2; ++tt) {
        const int T = 2*hw + tt;
        #pragma unroll
        for (int r = 0; r < 4; ++r) {
            b1c[tt][r] = b1[16*T + 4*quad + r];
            b2c[tt][r] = b2[16*T + 4*quad + r];
        }
    }
    #pragma unroll
    for (int c = 0; c < 3; ++c)
        #pragma unroll
        for (int r = 0; r < 4; ++r)
            b3c[c][r] = b3[(16*hw + 4*quad + r)*3 + c];

    // state z rows owned by this wave: h = 16*hw + 4*quad + r
    float z[4];
    #pragma unroll
    for (int r = 0; r < 4; ++r) {
        const int h = 16*hw + 4*quad + r;
        z[r] = w_enc[h] + b_enc[h];   // encoder([1.0])
    }
    const float dt = times[1] - times[0];

    // dq staging: threads 0..95 fetch one (tile,b,c) stream
    const int lcl = tid < 96 ? tid : 95;
    const int tld = lcl / 48;          // tile this stager feeds
    const int wn  = lcl - 48*tld;
    const int bl  = wn / 3;
    const int cc  = wn - 3*bl;
    const float* gp = grads + (long)(base + 16*tld + bl)*(TT*3) + cc;
    const bool dqact = tid < 96;
    float dqreg = gp[0];

    static constexpr float AT[6][5] = {
        {0.f, 0.f, 0.f, 0.f, 0.f},
        {0.161f, 0.f, 0.f, 0.f, 0.f},
        {-0.008480655492356989f, 0.335480655492357f, 0.f, 0.f, 0.f},
        {2.8971530571054935f, -6.359448489975075f, 4.3622954328695815f, 0.f, 0.f},
        {5.325864828439257f, -11.748883564062828f, 7.4955393428898365f,
         -0.09249506636175525f, 0.f},
        {5.86145544294642f, -12.92096931784711f, 8.159367898576159f,
         -0.071584973281401f, -0.028269050394068383f}};
    static constexpr float BT[6] = {
        0.09646076681806523f, 0.01f, 0.4798896504144996f, 1.379008574103742f,
        -3.290069515436081f, 2.324710524099774f};

    float kk[6][4];
    float dq0 = 0.f, dq1 = 0.f, dq2 = 0.f;

    for (int n = 0; n < NSTEP; ++n) {
        if (dqact) *(&dqbuf[tld][0][0] + (bl*4 + cc)) = dqreg * dt;

        #pragma unroll
        for (int s = 0; s < 6; ++s) {
            // stage argument (this wave's 16 rows), C-layout
            float za[4];
            #pragma unroll
            for (int r = 0; r < 4; ++r) {
                float v = z[r];
                #pragma unroll
                for (int j = 0; j < s; ++j) v += AT[s][j] * kk[j][r];
                za[r] = v;
            }
            {
                uint2 uH, uL;
                split_pack4(za[0], za[1], za[2], za[3], uH, uL);
                *(uint2*)&zbufH[t][col][16*hw + 4*quad] = uH;
                *(uint2*)&zbufL[t][col][16*hw + 4*quad] = uL;
            }
            __syncthreads();
            if (s == 0) {
                const float4 dv = *(const float4*)&dqbuf[t][col][0];
                dq0 = dv.x; dq1 = dv.y; dq2 = dv.z;
                const int nn = (n + 1 < NSTEP) ? (n + 1) : (NSTEP - 1);
                dqreg = gp[nn * 3];          // prefetch next step's gradient
            }
            const half8v zfH = *(const half8v*)&zbufH[t][col][quad*8];
            const half8v zfL = *(const half8v*)&zbufL[t][col][quad*8];

            // ---- layer 1: this wave's 32 rows ----
            #pragma unroll
            for (int tt = 0; tt < 2; ++tt) {
                floatx4 acc = {b1c[tt][0], b1c[tt][1], b1c[tt][2], b1c[tt][3]};
                acc = __builtin_amdgcn_mfma_f32_16x16x32_f16(w1fH[tt], zfH, acc, 0, 0, 0);
                acc = __builtin_amdgcn_mfma_f32_16x16x32_f16(w1fL[tt], zfH, acc, 0, 0, 0);
                acc = __builtin_amdgcn_mfma_f32_16x16x32_f16(w1fH[tt], zfL, acc, 0, 0, 0);
                uint2 uH, uL;
                split_pack4(fast_tanh(acc[0]), fast_tanh(acc[1]),
                            fast_tanh(acc[2]), fast_tanh(acc[3]), uH, uL);
                *(uint2*)&h1bufH[t][col][32*hw + 16*tt + 4*quad] = uH;
                *(uint2*)&h1bufL[t][col][32*hw + 16*tt + 4*quad] = uL;
            }
            __syncthreads();
            const half8v h1f0H = *(const half8v*)&h1bufH[t][col][quad*8];
            const half8v h1f1H = *(const half8v*)&h1bufH[t][col][32 + quad*8];
            const half8v h1f0L = *(const half8v*)&h1bufL[t][col][quad*8];
            const half8v h1f1L = *(const half8v*)&h1bufL[t][col][32 + quad*8];

            // ---- layer 2: this wave's 32 rows ----
            #pragma unroll
            for (int tt = 0; tt < 2; ++tt) {
                floatx4 acc = {b2c[tt][0], b2c[tt][1], b2c[tt][2], b2c[tt][3]};
                acc = __builtin_amdgcn_mfma_f32_16x16x32_f16(w2fH[tt][0], h1f0H, acc, 0, 0, 0);
                acc = __builtin_amdgcn_mfma_f32_16x16x32_f16(w2fL[tt][0], h1f0H, acc, 0, 0, 0);
                acc = __builtin_amdgcn_mfma_f32_16x16x32_f16(w2fH[tt][0], h1f0L, acc, 0, 0, 0);
                acc = __builtin_amdgcn_mfma_f32_16x16x32_f16(w2fH[tt][1], h1f1H, acc, 0, 0, 0);
                acc = __builtin_amdgcn_mfma_f32_16x16x32_f16(w2fL[tt][1], h1f1H, acc, 0, 0, 0);
                acc = __builtin_amdgcn_mfma_f32_16x16x32_f16(w2fH[tt][1], h1f1L, acc, 0, 0, 0);
                uint2 uH, uL;
                split_pack4(fast_tanh(acc[0]), fast_tanh(acc[1]),
                            fast_tanh(acc[2]), fast_tanh(acc[3]), uH, uL);
                *(uint2*)&h2bufH[t][col][32*hw + 16*tt + 4*quad] = uH;
                *(uint2*)&h2bufL[t][col][32*hw + 16*tt + 4*quad] = uL;
            }
            __syncthreads();
            const half8v h2f0H = *(const half8v*)&h2bufH[t][col][quad*8];
            const half8v h2f1H = *(const half8v*)&h2bufH[t][col][32 + quad*8];
            const half8v h2f0L = *(const half8v*)&h2bufL[t][col][quad*8];
            const half8v h2f1L = *(const half8v*)&h2bufL[t][col][32 + quad*8];

            // ---- layer 3: c = 0..2 of this wave's hw half ----
            floatx4 a3[3];
            #pragma unroll
            for (int c = 0; c < 3; ++c) {
                floatx4 acc = {b3c[c][0], b3c[c][1], b3c[c][2], b3c[c][3]};
                acc = __builtin_amdgcn_mfma_f32_16x16x32_f16(w3fH[c][0], h2f0H, acc, 0, 0, 0);
                acc = __builtin_amdgcn_mfma_f32_16x16x32_f16(w3fL[c][0], h2f0H, acc, 0, 0, 0);
                acc = __builtin_amdgcn_mfma_f32_16x16x32_f16(w3fH[c][0], h2f0L, acc, 0, 0, 0);
                acc = __builtin_amdgcn_mfma_f32_16x16x32_f16(w3fH[c][1], h2f1H, acc, 0, 0, 0);
                acc = __builtin_amdgcn_mfma_f32_16x16x32_f16(w3fL[c][1], h2f1H, acc, 0, 0, 0);
                acc = __builtin_amdgcn_mfma_f32_16x16x32_f16(w3fH[c][1], h2f1L, acc, 0, 0, 0);
                a3[c] = acc;
            }
            #pragma unroll
            for (int r = 0; r < 4; ++r)
                kk[s][r] = a3[0][r]*dq0 + a3[1][r]*dq1 + a3[2][r]*dq2;
        }

        // z += sum_i B_i * k_i
        #pragma unroll
        for (int r = 0; r < 4; ++r) {
            float v = z[r];
            #pragma unroll
            for (int j = 0; j < 6; ++j) v += BT[j] * kk[j][r];
            z[r] = v;
        }
    }

    // ---- readout: logit[b] = sum_h z[h][b]*w_ro[h] + b_ro; out = sigmoid ----
    float part = 0.f;
    #pragma unroll
    for (int r = 0; r < 4; ++r)
        part += z[r] * w_ro[16*hw + 4*quad + r];
    part += __shfl_xor(part, 16, 64);
    part += __shfl_xor(part, 32, 64);
    if (hw == 1 && lane < 16) robuf[t][col] = part;
    __syncthreads();
    if (hw == 0 && lane < 16) {
        const float x = part + robuf[t][col] + b_ro[0];
        out[base + 16*t + col] = FAST_RCP(1.0f + FAST_EXP2(-1.4426950408889634f * x));
    }
}

extern "C" void kernel_launch(void* const* d_in, const int* in_sizes, int n_in,
                              void* d_out, int out_size, void* d_ws, size_t ws_size,
                              hipStream_t stream) {
    const float* times = (const float*)d_in[0];
    const float* grads = (const float*)d_in[1];
    const float* w1    = (const float*)d_in[2];
    const float* b1    = (const float*)d_in[3];
    const float* w2    = (const float*)d_in[4];
    const float* b2    = (const float*)d_in[5];
    const float* w3    = (const float*)d_in[6];
    const float* b3    = (const float*)d_in[7];
    const float* w_enc = (const float*)d_in[8];
    const float* b_enc = (const float*)d_in[9];
    const float* w_ro  = (const float*)d_in[10];
    const float* b_ro  = (const float*)d_in[11];

    const int B = in_sizes[1] / (TT * 3);   // 16384
    dim3 grid(B / 32), block(256);
    hipLaunchKernelGGL(cde_fused, grid, block, 0, stream,
                       times, grads, w1, b1, w2, b2, w3, b3,
                       w_enc, b_enc, w_ro, b_ro, (float*)d_out);
}